// Round 1
// baseline (1657.491 us; speedup 1.0000x reference)
//
#include <hip/hip_runtime.h>

#define H_  128
#define B_  64
#define N_  100
#define M_  2000
#define TM  128
#define NT  512

// B-buffer swizzle: spread column-bits 5..6 into bank bits 2..3 (float index, arg multiple of 4)
__device__ __forceinline__ int bswz(int a) { return a ^ (((a >> 5) & 3) << 2); }
// A-buffer swizzle: row-dependent rotation of 16B chunks (row-major [128][128], no pad)
__device__ __forceinline__ int aswz(int m, int f) { return (m * H_ + f) ^ (((m >> 2) & 3) << 2); }

__global__ void __launch_bounds__(NT, 1)
vrp_fused(const float* __restrict__ e_emb,
          const int* __restrict__ reloc_idx,
          const int* __restrict__ cross_idx,
          const int* __restrict__ twopt_idx,
          const float* __restrict__ reloc_W1, const float* __restrict__ reloc_b1,
          const float* __restrict__ reloc_W2, const float* __restrict__ reloc_b2,
          const float* __restrict__ cross_W1, const float* __restrict__ cross_b1,
          const float* __restrict__ cross_W2, const float* __restrict__ cross_b2,
          const float* __restrict__ an_W1, const float* __restrict__ an_b1,
          const float* __restrict__ an_W2, const float* __restrict__ an_b2,
          const float* __restrict__ an_W3, const float* __restrict__ an_b3,
          const float* __restrict__ an_Wo, const float* __restrict__ an_bo,
          float* __restrict__ out)
{
    __shared__ float Ab[TM * H_];   // 64 KiB: feat slot / hidden activations
    __shared__ float Bb[H_ * H_];   // 64 KiB: current 128x128 weight block (bswz'd)

    const int bid  = blockIdx.x;
    const int type = bid >> 10;          // 0=reloc 1=cross 2=twopt
    const int rr   = bid & 1023;
    const int b    = rr >> 4;            // instance
    const int tile = rr & 15;            // move tile (128 moves)

    const int*   idxp;
    const float *W1, *b1v, *W2, *b2v;
    int KS;
    if (type == 0) { idxp = reloc_idx; W1 = reloc_W1; b1v = reloc_b1; W2 = reloc_W2; b2v = reloc_b2; KS = 6; }
    else           { idxp = (type == 1) ? cross_idx : twopt_idx;
                     W1 = cross_W1; b1v = cross_b1; W2 = cross_W2; b2v = cross_b2; KS = 4; }

    const int t  = threadIdx.x;
    const int n0 = (t & 15) * 8;     // output columns n0..n0+7
    const int m0 = (t >> 4) * 4;     // rows m0..m0+3

    float acc[4][8];
    #pragma unroll
    for (int i = 0; i < 4; ++i)
        #pragma unroll
        for (int j = 0; j < 8; ++j) acc[i][j] = 0.f;

    // K=128 register-tiled GEMM: acc[4][8] += Ab[m0..m0+3][:] * Bb[:][n0..n0+7]
    auto gemm = [&]() {
        #pragma unroll 2
        for (int kb = 0; kb < H_; kb += 4) {
            float aA[4][4];
            #pragma unroll
            for (int i = 0; i < 4; ++i)
                *(float4*)aA[i] = *(const float4*)&Ab[aswz(m0 + i, kb)];
            #pragma unroll
            for (int kk = 0; kk < 4; ++kk) {
                float bv[8];
                *(float4*)&bv[0] = *(const float4*)&Bb[bswz((kb + kk) * H_ + n0)];
                *(float4*)&bv[4] = *(const float4*)&Bb[bswz((kb + kk) * H_ + n0 + 4)];
                #pragma unroll
                for (int i = 0; i < 4; ++i)
                    #pragma unroll
                    for (int j = 0; j < 8; ++j)
                        acc[i][j] += aA[i][kk] * bv[j];
            }
        }
    };

    auto stageB = [&](const float* W) {
        const float4* src = (const float4*)W;
        #pragma unroll
        for (int it = 0; it < 8; ++it) {
            int lin4 = t + NT * it;              // 0..4095 float4s
            int k = lin4 >> 5, c4 = lin4 & 31;
            float4 v = src[lin4];
            *(float4*)&Bb[bswz(k * H_ + c4 * 4)] = v;
        }
    };

    // ---------------- GEMM1: feat @ W1, streamed per edge slot ----------------
    for (int s = 0; s < KS; ++s) {
        stageB(W1 + (size_t)s * H_ * H_);
        // gather 128 edge rows for slot s into Ab
        const float4* rows[8];
        #pragma unroll
        for (int it = 0; it < 8; ++it) {
            int lin4 = t + NT * it;
            int m = lin4 >> 5;
            int mg = tile * TM + m; mg = (mg < M_) ? mg : (M_ - 1);
            const int* ip = idxp + ((((size_t)b * M_ + mg) * KS + s) << 1);
            int ii = ip[0], jj = ip[1];
            rows[it] = (const float4*)(e_emb + (((size_t)b * N_ + ii) * N_ + jj) * H_);
        }
        #pragma unroll
        for (int it = 0; it < 8; ++it) {
            int lin4 = t + NT * it;
            int m = lin4 >> 5, c4 = lin4 & 31;
            float4 v = rows[it][c4];
            *(float4*)&Ab[aswz(m, c4 * 4)] = v;
        }
        __syncthreads();
        gemm();
        __syncthreads();
    }

    // step: h = acc (+bias, opt relu) -> Ab; stage next W; acc = h @ W
    auto step = [&](const float* bias, bool relu, const float* nextW) {
        float bb[8];
        *(float4*)&bb[0] = *(const float4*)&bias[n0];
        *(float4*)&bb[4] = *(const float4*)&bias[n0 + 4];
        #pragma unroll
        for (int i = 0; i < 4; ++i) {
            float hv[8];
            #pragma unroll
            for (int j = 0; j < 8; ++j) {
                float v = acc[i][j] + bb[j];
                hv[j] = relu ? fmaxf(v, 0.f) : v;
            }
            *(float4*)&Ab[aswz(m0 + i, n0)]     = *(float4*)&hv[0];
            *(float4*)&Ab[aswz(m0 + i, n0 + 4)] = *(float4*)&hv[4];
        }
        stageB(nextW);
        __syncthreads();
        #pragma unroll
        for (int i = 0; i < 4; ++i)
            #pragma unroll
            for (int j = 0; j < 8; ++j) acc[i][j] = 0.f;
        gemm();
        __syncthreads();
    };

    step(b1v,   true,  W2);      // h1  = relu(feat@W1 + b1); acc = h1@W2
    step(b2v,   false, an_W1);   // emb = acc + b2 (linear);  acc = emb@anW1
    step(an_b1, true,  an_W2);   // h   = relu(acc + anb1);   acc = h@anW2
    step(an_b2, true,  an_W3);   // h   = relu(acc + anb2);   acc = h@anW3

    // final hidden: h3 = relu(acc + an_b3) -> Ab
    {
        float bb[8];
        *(float4*)&bb[0] = *(const float4*)&an_b3[n0];
        *(float4*)&bb[4] = *(const float4*)&an_b3[n0 + 4];
        #pragma unroll
        for (int i = 0; i < 4; ++i) {
            float hv[8];
            #pragma unroll
            for (int j = 0; j < 8; ++j)
                hv[j] = fmaxf(acc[i][j] + bb[j], 0.f);
            *(float4*)&Ab[aswz(m0 + i, n0)]     = *(float4*)&hv[0];
            *(float4*)&Ab[aswz(m0 + i, n0 + 4)] = *(float4*)&hv[4];
        }
    }
    __syncthreads();

    // logit[m] = h3[m][:] . Wo + bo  (4 lanes per move, shfl reduce)
    {
        int m = t >> 2, q = t & 3;
        float sum = 0.f;
        #pragma unroll
        for (int kk = 0; kk < 32; kk += 4) {
            int f = q * 32 + kk;
            float4 hv = *(const float4*)&Ab[aswz(m, f)];
            float4 wv = *(const float4*)&an_Wo[f];
            sum += hv.x * wv.x + hv.y * wv.y + hv.z * wv.z + hv.w * wv.w;
        }
        sum += __shfl_xor(sum, 1);
        sum += __shfl_xor(sum, 2);
        if (q == 0) {
            int mg = tile * TM + m;
            if (mg < M_)
                out[((size_t)b * 3 + type) * M_ + mg] = sum + an_bo[0];
        }
    }
}

extern "C" void kernel_launch(void* const* d_in, const int* in_sizes, int n_in,
                              void* d_out, int out_size, void* d_ws, size_t ws_size,
                              hipStream_t stream) {
    const float* e_emb     = (const float*)d_in[0];
    const int*   reloc_idx = (const int*)  d_in[1];
    const int*   cross_idx = (const int*)  d_in[2];
    const int*   twopt_idx = (const int*)  d_in[3];
    const float* reloc_W1  = (const float*)d_in[4];
    const float* reloc_b1  = (const float*)d_in[5];
    const float* reloc_W2  = (const float*)d_in[6];
    const float* reloc_b2  = (const float*)d_in[7];
    const float* cross_W1  = (const float*)d_in[8];
    const float* cross_b1  = (const float*)d_in[9];
    const float* cross_W2  = (const float*)d_in[10];
    const float* cross_b2  = (const float*)d_in[11];
    const float* an_W1     = (const float*)d_in[12];
    const float* an_b1     = (const float*)d_in[13];
    const float* an_W2     = (const float*)d_in[14];
    const float* an_b2     = (const float*)d_in[15];
    const float* an_W3     = (const float*)d_in[16];
    const float* an_b3     = (const float*)d_in[17];
    const float* an_Wo     = (const float*)d_in[18];
    const float* an_bo     = (const float*)d_in[19];
    float* out = (float*)d_out;

    dim3 grid(3 * B_ * (  (M_ + TM - 1) / TM  ));   // 3 * 64 * 16 = 3072
    dim3 block(NT);
    hipLaunchKernelGGL(vrp_fused, grid, block, 0, stream,
                       e_emb, reloc_idx, cross_idx, twopt_idx,
                       reloc_W1, reloc_b1, reloc_W2, reloc_b2,
                       cross_W1, cross_b1, cross_W2, cross_b2,
                       an_W1, an_b1, an_W2, an_b2, an_W3, an_b3, an_Wo, an_bo,
                       out);
}

// Round 5
// 436.395 us; speedup vs baseline: 3.7981x; 3.7981x over previous
//
#include <hip/hip_runtime.h>

#define H_  128
#define B_  64
#define N_  100
#define M_  2000
#define NT  512

// ws layout (ushort elements): per matrix [hi plane [128][K], lo plane [128][K]] , WT[n][k] = W[k][n]
#define RW1T 0
#define RW2T 196608
#define CW1T 229376
#define CW2T 360448
#define AW1T 393216
#define AW2T 425984
#define AW3T 458752
#define WT_ELEMS 491520   // ushorts (~983 KB)

typedef __attribute__((ext_vector_type(8)))  __bf16 bf16x8;
typedef __attribute__((ext_vector_type(16))) float  f32x16;

__device__ __forceinline__ unsigned short f2bf(float f) {
    unsigned int u = __float_as_uint(f);
    u = (u + 0x7FFFu + ((u >> 16) & 1u)) >> 16;
    return (unsigned short)u;
}
__device__ __forceinline__ float bf2f(unsigned short h) {
    return __uint_as_float(((unsigned int)h) << 16);
}

// -------- prep: build transposed hi/lo bf16 weight planes in ws --------
__global__ void __launch_bounds__(256)
wt_prep(const float* __restrict__ s0, const float* __restrict__ s1,
        const float* __restrict__ s2, const float* __restrict__ s3,
        const float* __restrict__ s4, const float* __restrict__ s5,
        const float* __restrict__ s6, unsigned short* __restrict__ wt)
{
    int g = blockIdx.x * 256 + threadIdx.x;
    if (g >= 245760) return;
    const float* src; int e, K, base;
    if      (g <  98304) { src = s0; e = g;          K = 768; base = RW1T; }
    else if (g < 114688) { src = s1; e = g -  98304; K = 128; base = RW2T; }
    else if (g < 180224) { src = s2; e = g - 114688; K = 512; base = CW1T; }
    else if (g < 196608) { src = s3; e = g - 180224; K = 128; base = CW2T; }
    else if (g < 212992) { src = s4; e = g - 196608; K = 128; base = AW1T; }
    else if (g < 229376) { src = s5; e = g - 212992; K = 128; base = AW2T; }
    else                 { src = s6; e = g - 229376; K = 128; base = AW3T; }
    int k = e >> 7, n = e & 127;          // src is W[k][n], row-major n-contiguous
    float v = src[e];
    unsigned short hi = f2bf(v);
    unsigned short lo = f2bf(v - bf2f(hi));
    wt[base + n * K + k] = hi;
    wt[base + 128 * K + n * K + k] = lo;
}

// -------- main fused kernel --------
__global__ void __launch_bounds__(NT, 1)
vrp_mfma(const float* __restrict__ e_emb,
         const int* __restrict__ reloc_idx, const int* __restrict__ cross_idx,
         const int* __restrict__ twopt_idx,
         const float* __restrict__ reloc_b1, const float* __restrict__ reloc_b2,
         const float* __restrict__ cross_b1, const float* __restrict__ cross_b2,
         const float* __restrict__ an_b1, const float* __restrict__ an_b2,
         const float* __restrict__ an_b3,
         const float* __restrict__ an_Wo, const float* __restrict__ an_bo,
         const unsigned short* __restrict__ wt,
         float* __restrict__ out)
{
    // act tiles [m 128][k 128] and weight-T tiles [n 128][k 128], hi/lo planes,
    // bf16, XOR-swizzled: byte ^= (row&15)<<4  (keeps 16B frag reads conflict-free)
    __shared__ __align__(16) unsigned short Ah[H_ * H_], Al[H_ * H_];
    __shared__ __align__(16) unsigned short Bh[H_ * H_], Bl[H_ * H_];
    __shared__ __align__(16) float bias_all[6 * H_];   // b1,b2,anb1,anb2,anb3,Wo
    __shared__ float red[4 * H_];

    const int t   = threadIdx.x;
    const int bid = blockIdx.x;
    const int type    = bid >> 10;      // 0=reloc 1=cross 2=twopt
    const int rr      = bid & 1023;
    const int b       = rr >> 4;
    const int blkTile = rr & 15;        // 128-move tile

    const int w    = t >> 6;            // wave 0..7
    const int l    = t & 63;
    const int l31  = l & 31;
    const int oct  = l >> 5;            // k-octet select
    const int ntile = w & 3;            // n-range ntile*32
    const int mhalf = w >> 2;           // m-range mhalf*64 (2 m-tiles)

    const int*  idxp = (type == 0) ? reloc_idx : (type == 1) ? cross_idx : twopt_idx;
    const int   KS   = (type == 0) ? 6 : 4;
    const int   w1t  = (type == 0) ? RW1T : CW1T;
    const int   k1   = (type == 0) ? 768 : 512;
    const int   w2t  = (type == 0) ? RW2T : CW2T;
    const float* b1p = (type == 0) ? reloc_b1 : cross_b1;
    const float* b2p = (type == 0) ? reloc_b2 : cross_b2;

    // BUGFIX (R2): 6*H_=768 > NT=512 — must loop, not mask. Slots 4 (an_b3)
    // and 5 (an_Wo) were previously uninitialized LDS.
    for (int i = t; i < 6 * H_; i += NT) {
        int g = i >> 7, ii = i & 127;
        const float* p = (g == 0) ? b1p : (g == 1) ? b2p : (g == 2) ? an_b1
                       : (g == 3) ? an_b2 : (g == 4) ? an_b3 : an_Wo;
        bias_all[i] = p[ii];
    }

    f32x16 acc0, acc1;
    #pragma unroll
    for (int i = 0; i < 16; ++i) { acc0[i] = 0.f; acc1[i] = 0.f; }

    auto zeroAcc = [&]() {
        #pragma unroll
        for (int i = 0; i < 16; ++i) { acc0[i] = 0.f; acc1[i] = 0.f; }
    };

    // stage one 128x128 WT window (hi+lo) into Bh/Bl
    auto stageB = [&](int matOff, int matK, int kOff) {
        #pragma unroll
        for (int p = 0; p < 2; ++p) {
            const unsigned short* src = wt + matOff + p * (H_ * matK);
            char* dst = (char*)(p ? Bl : Bh);
            #pragma unroll
            for (int it = 0; it < 4; ++it) {
                int c = t + NT * it;            // 2048 16B chunks
                int n = c >> 4, ch = c & 15;
                uint4 v = *(const uint4*)(src + n * matK + kOff + ch * 8);
                *(uint4*)(dst + n * 256 + ((ch * 16) ^ ((n & 15) << 4))) = v;
            }
        }
    };

    // gather slot-s edge rows -> Ah/Al (fp32 -> hi/lo bf16 split)
    auto stageA_gather = [&](int s) {
        #pragma unroll
        for (int it = 0; it < 8; ++it) {
            int c = t + NT * it;                // 4096 float4s
            int m = c >> 5, f4 = c & 31;
            int mg = blkTile * 128 + m; mg = (mg < M_) ? mg : (M_ - 1);
            const int* ip = idxp + (((b * M_ + mg) * KS + s) << 1);
            int ii = ip[0], jj = ip[1];
            const float4* row = (const float4*)(e_emb + (((size_t)b * N_ + ii) * N_ + jj) * H_);
            float4 v = row[f4];
            float va[4] = {v.x, v.y, v.z, v.w};
            unsigned short hs[4], ls[4];
            #pragma unroll
            for (int r2 = 0; r2 < 4; ++r2) {
                hs[r2] = f2bf(va[r2]);
                ls[r2] = f2bf(va[r2] - bf2f(hs[r2]));
            }
            uint2 hw, lw;
            hw.x = hs[0] | ((unsigned)hs[1] << 16); hw.y = hs[2] | ((unsigned)hs[3] << 16);
            lw.x = ls[0] | ((unsigned)ls[1] << 16); lw.y = ls[2] | ((unsigned)ls[3] << 16);
            int off = m * 256 + ((f4 * 8) ^ ((m & 15) << 4));
            *(uint2*)((char*)Ah + off) = hw;
            *(uint2*)((char*)Al + off) = lw;
        }
    };

    // one K=128 unit: acc(+)= WT_frag x actT_frag  (computes C^T tiles)
    auto runUnit = [&]() {
        const int nrow  = ntile * 32 + l31;
        const int mrow  = mhalf * 64 + l31;
        const int nbase = nrow * 256, Xn = (nrow & 15) << 4;
        const int mbase = mrow * 256, Xm = (mrow & 15) << 4;
        #pragma unroll
        for (int ks = 0; ks < 8; ++ks) {
            int ka   = ks * 32 + oct * 16;       // k byte offset within row
            int offW = nbase + (ka ^ Xn);
            int offA = mbase + (ka ^ Xm);
            bf16x8 wh  = *(const bf16x8*)((const char*)Bh + offW);
            bf16x8 wl  = *(const bf16x8*)((const char*)Bl + offW);
            bf16x8 a0h = *(const bf16x8*)((const char*)Ah + offA);
            bf16x8 a0l = *(const bf16x8*)((const char*)Al + offA);
            bf16x8 a1h = *(const bf16x8*)((const char*)Ah + offA + 32 * 256);
            bf16x8 a1l = *(const bf16x8*)((const char*)Al + offA + 32 * 256);
            acc0 = __builtin_amdgcn_mfma_f32_32x32x16_bf16(wh, a0h, acc0, 0, 0, 0);
            acc0 = __builtin_amdgcn_mfma_f32_32x32x16_bf16(wh, a0l, acc0, 0, 0, 0);
            acc0 = __builtin_amdgcn_mfma_f32_32x32x16_bf16(wl, a0h, acc0, 0, 0, 0);
            acc1 = __builtin_amdgcn_mfma_f32_32x32x16_bf16(wh, a1h, acc1, 0, 0, 0);
            acc1 = __builtin_amdgcn_mfma_f32_32x32x16_bf16(wh, a1l, acc1, 0, 0, 0);
            acc1 = __builtin_amdgcn_mfma_f32_32x32x16_bf16(wl, a1h, acc1, 0, 0, 0);
        }
    };

    // acc (=C^T: lane col = m, regs = n) -> bias/act -> hi/lo bf16 -> Ah/Al
    auto writeback = [&](int biasSlot, bool doRelu) {
        const float* bp = &bias_all[biasSlot * H_];
        #pragma unroll
        for (int tl = 0; tl < 2; ++tl) {
            int m  = mhalf * 64 + tl * 32 + l31;
            int mb = m * 256, Xm2 = (m & 15) << 4;
            #pragma unroll
            for (int q = 0; q < 4; ++q) {
                int n0 = ntile * 32 + q * 8 + oct * 4;   // 4 consecutive n
                float4 bq = *(const float4*)&bp[n0];
                float ba[4] = {bq.x, bq.y, bq.z, bq.w};
                unsigned short hs[4], ls[4];
                #pragma unroll
                for (int r2 = 0; r2 < 4; ++r2) {
                    float v = (tl ? acc1[q * 4 + r2] : acc0[q * 4 + r2]) + ba[r2];
                    if (doRelu) v = fmaxf(v, 0.f);
                    hs[r2] = f2bf(v);
                    ls[r2] = f2bf(v - bf2f(hs[r2]));
                }
                uint2 hw, lw;
                hw.x = hs[0] | ((unsigned)hs[1] << 16); hw.y = hs[2] | ((unsigned)hs[3] << 16);
                lw.x = ls[0] | ((unsigned)ls[1] << 16); lw.y = ls[2] | ((unsigned)ls[3] << 16);
                int off = mb + ((n0 * 2) ^ Xm2);
                *(uint2*)((char*)Ah + off) = hw;
                *(uint2*)((char*)Al + off) = lw;
            }
        }
    };

    // ---- GEMM1: stream K over edge slots ----
    for (int s = 0; s < KS; ++s) {
        stageB(w1t, k1, s * 128);
        stageA_gather(s);
        __syncthreads();
        runUnit();
        __syncthreads();
    }
    // ---- chained 128x128 layers ----
    writeback(0, true);  stageB(w2t, 128, 0);  __syncthreads(); zeroAcc(); runUnit(); __syncthreads();
    writeback(1, false); stageB(AW1T, 128, 0); __syncthreads(); zeroAcc(); runUnit(); __syncthreads();
    writeback(2, true);  stageB(AW2T, 128, 0); __syncthreads(); zeroAcc(); runUnit(); __syncthreads();
    writeback(3, true);  stageB(AW3T, 128, 0); __syncthreads(); zeroAcc(); runUnit(); __syncthreads();

    // ---- final: logit = relu(acc + an_b3) . Wo + bo, straight from accumulators ----
    float p0 = 0.f, p1 = 0.f;
    {
        const float* b3p = &bias_all[4 * H_];
        const float* wop = &bias_all[5 * H_];
        #pragma unroll
        for (int q = 0; q < 4; ++q) {
            int n0 = ntile * 32 + q * 8 + oct * 4;
            float4 bq = *(const float4*)&b3p[n0];
            float4 wq = *(const float4*)&wop[n0];
            float ba[4] = {bq.x, bq.y, bq.z, bq.w};
            float wa[4] = {wq.x, wq.y, wq.z, wq.w};
            #pragma unroll
            for (int r2 = 0; r2 < 4; ++r2) {
                p0 += fmaxf(acc0[q * 4 + r2] + ba[r2], 0.f) * wa[r2];
                p1 += fmaxf(acc1[q * 4 + r2] + ba[r2], 0.f) * wa[r2];
            }
        }
    }
    p0 += __shfl_xor(p0, 32);
    p1 += __shfl_xor(p1, 32);
    if (l < 32) {
        red[ntile * H_ + mhalf * 64 + l31]      = p0;
        red[ntile * H_ + mhalf * 64 + 32 + l31] = p1;
    }
    __syncthreads();
    if (t < 128) {
        float sres = red[t] + red[H_ + t] + red[2 * H_ + t] + red[3 * H_ + t] + an_bo[0];
        int mg = blkTile * 128 + t;
        if (mg < M_)
            out[((size_t)(b * 3 + type)) * M_ + mg] = sres;
    }
}

extern "C" void kernel_launch(void* const* d_in, const int* in_sizes, int n_in,
                              void* d_out, int out_size, void* d_ws, size_t ws_size,
                              hipStream_t stream) {
    const float* e_emb     = (const float*)d_in[0];
    const int*   reloc_idx = (const int*)  d_in[1];
    const int*   cross_idx = (const int*)  d_in[2];
    const int*   twopt_idx = (const int*)  d_in[3];
    const float* reloc_W1  = (const float*)d_in[4];
    const float* reloc_b1  = (const float*)d_in[5];
    const float* reloc_W2  = (const float*)d_in[6];
    const float* reloc_b2  = (const float*)d_in[7];
    const float* cross_W1  = (const float*)d_in[8];
    const float* cross_b1  = (const float*)d_in[9];
    const float* cross_W2  = (const float*)d_in[10];
    const float* cross_b2  = (const float*)d_in[11];
    const float* an_W1     = (const float*)d_in[12];
    const float* an_b1     = (const float*)d_in[13];
    const float* an_W2     = (const float*)d_in[14];
    const float* an_b2     = (const float*)d_in[15];
    const float* an_W3     = (const float*)d_in[16];
    const float* an_b3     = (const float*)d_in[17];
    const float* an_Wo     = (const float*)d_in[18];
    const float* an_bo     = (const float*)d_in[19];
    float* out = (float*)d_out;
    unsigned short* wt = (unsigned short*)d_ws;   // needs ~983 KB of ws

    hipLaunchKernelGGL(wt_prep, dim3(960), dim3(256), 0, stream,
                       reloc_W1, reloc_W2, cross_W1, cross_W2, an_W1, an_W2, an_W3, wt);
    hipLaunchKernelGGL(vrp_mfma, dim3(3 * B_ * 16), dim3(NT), 0, stream,
                       e_emb, reloc_idx, cross_idx, twopt_idx,
                       reloc_b1, reloc_b2, cross_b1, cross_b2,
                       an_b1, an_b2, an_b3, an_Wo, an_bo, wt, out);
}

// Round 6
// 433.208 us; speedup vs baseline: 3.8261x; 1.0074x over previous
//
#include <hip/hip_runtime.h>

#define H_  128
#define B_  64
#define N_  100
#define M_  2000
#define NT  512

// ws layout (ushort units): per matrix, per 128-k window: a 64 KB LDS *image*
// [hi plane 32 KB][lo plane 32 KB], XOR-swizzle (byte ^= (n&15)<<4 per 16B chunk)
// PRE-APPLIED so stageB is a linear global_load_lds copy (rule #21: linear dest
// + inverse-swizzled source + swizzled read).
#define RW1T 0         // 6 windows
#define RW2T 196608    // 1 window
#define CW1T 229376    // 4 windows
#define CW2T 360448    // 1
#define AW1T 393216    // 1
#define AW2T 425984    // 1
#define AW3T 458752    // 1
#define WT_ELEMS 491520   // ushorts (~983 KB)
#define WIN_U 32768       // ushorts per 64 KB window image
#define PLANE_U 16384     // ushorts per 32 KB plane image

typedef __attribute__((ext_vector_type(8)))  __bf16 bf16x8;
typedef __attribute__((ext_vector_type(16))) float  f32x16;

__device__ __forceinline__ unsigned short f2bf(float f) {
    unsigned int u = __float_as_uint(f);
    u = (u + 0x7FFFu + ((u >> 16) & 1u)) >> 16;
    return (unsigned short)u;
}
__device__ __forceinline__ float bf2f(unsigned short h) {
    return __uint_as_float(((unsigned int)h) << 16);
}

// async global->LDS, 16 B per lane (m97 pattern)
__device__ __forceinline__ void gload_lds16(const void* g, void* l) {
    __builtin_amdgcn_global_load_lds(
        (const __attribute__((address_space(1))) unsigned int*)g,
        (__attribute__((address_space(3))) unsigned int*)l,
        16, 0, 0);
}

// -------- prep: build swizzled hi/lo window images in ws --------
__global__ void __launch_bounds__(256)
wt_prep(const float* __restrict__ s0, const float* __restrict__ s1,
        const float* __restrict__ s2, const float* __restrict__ s3,
        const float* __restrict__ s4, const float* __restrict__ s5,
        const float* __restrict__ s6, unsigned short* __restrict__ wt)
{
    int g = blockIdx.x * 256 + threadIdx.x;
    if (g >= 245760) return;
    const float* src; int e, base;
    if      (g <  98304) { src = s0; e = g;          base = RW1T; }
    else if (g < 114688) { src = s1; e = g -  98304; base = RW2T; }
    else if (g < 180224) { src = s2; e = g - 114688; base = CW1T; }
    else if (g < 196608) { src = s3; e = g - 180224; base = CW2T; }
    else if (g < 212992) { src = s4; e = g - 196608; base = AW1T; }
    else if (g < 229376) { src = s5; e = g - 212992; base = AW2T; }
    else                 { src = s6; e = g - 229376; base = AW3T; }
    int k = e >> 7, n = e & 127;          // src is W[k][n], row-major n-contiguous
    float v = src[e];
    unsigned short hi = f2bf(v);
    unsigned short lo = f2bf(v - bf2f(hi));
    int w  = k >> 7, kk = k & 127;        // window, k-within-window
    int ch = kk >> 3, ib = kk & 7;        // 16B chunk, elem-in-chunk
    int byteoff = n * 256 + ((ch * 16) ^ ((n & 15) << 4)) + ib * 2;
    size_t uoff = (size_t)base + (size_t)w * WIN_U + (byteoff >> 1);
    wt[uoff]           = hi;
    wt[uoff + PLANE_U] = lo;
}

// -------- main fused kernel --------
__global__ void __launch_bounds__(NT, 1)
vrp_mfma(const float* __restrict__ e_emb,
         const int* __restrict__ reloc_idx, const int* __restrict__ cross_idx,
         const int* __restrict__ twopt_idx,
         const float* __restrict__ reloc_b1, const float* __restrict__ reloc_b2,
         const float* __restrict__ cross_b1, const float* __restrict__ cross_b2,
         const float* __restrict__ an_b1, const float* __restrict__ an_b2,
         const float* __restrict__ an_b3,
         const float* __restrict__ an_Wo, const float* __restrict__ an_bo,
         const unsigned short* __restrict__ wt,
         float* __restrict__ out)
{
    __shared__ __align__(16) unsigned short Ah[H_ * H_], Al[H_ * H_];
    __shared__ __align__(16) unsigned short Bh[H_ * H_], Bl[H_ * H_];
    __shared__ __align__(16) float bias_all[6 * H_];   // b1,b2,anb1,anb2,anb3,Wo
    __shared__ float red[4 * H_];

    const int t   = threadIdx.x;
    const int bid = blockIdx.x;
    const int type    = bid >> 10;      // 0=reloc 1=cross 2=twopt
    const int rr      = bid & 1023;
    const int b       = rr >> 4;
    const int blkTile = rr & 15;        // 128-move tile

    const int w    = t >> 6;            // wave 0..7
    const int l    = t & 63;
    const int l31  = l & 31;
    const int oct  = l >> 5;            // k-octet select
    const int ntile = w & 3;            // n-range ntile*32
    const int mhalf = w >> 2;           // m-range mhalf*64 (2 m-tiles)

    const int*  idxp = (type == 0) ? reloc_idx : (type == 1) ? cross_idx : twopt_idx;
    const int   KS   = (type == 0) ? 6 : 4;
    const int   w1t  = (type == 0) ? RW1T : CW1T;
    const int   w2t  = (type == 0) ? RW2T : CW2T;
    const float* b1p = (type == 0) ? reloc_b1 : cross_b1;
    const float* b2p = (type == 0) ? reloc_b2 : cross_b2;

    // 6*H_=768 > NT: strided loop (R2 bugfix)
    for (int i = t; i < 6 * H_; i += NT) {
        int g = i >> 7, ii = i & 127;
        const float* p = (g == 0) ? b1p : (g == 1) ? b2p : (g == 2) ? an_b1
                       : (g == 3) ? an_b2 : (g == 4) ? an_b3 : an_Wo;
        bias_all[i] = p[ii];
    }

    f32x16 acc0, acc1;
    #pragma unroll
    for (int i = 0; i < 16; ++i) { acc0[i] = 0.f; acc1[i] = 0.f; }

    auto zeroAcc = [&]() {
        #pragma unroll
        for (int i = 0; i < 16; ++i) { acc0[i] = 0.f; acc1[i] = 0.f; }
    };

    // async-stage one pre-swizzled 64 KB window image into Bh/Bl (issue only;
    // drained by the next __syncthreads). Fully coalesced, no regs, no VALU.
    auto stageB = [&](int winBase) {
        const char* hsrc = (const char*)(wt + winBase);
        const char* lsrc = hsrc + 32768;
        #pragma unroll
        for (int it = 0; it < 4; ++it) {
            int off = (t + NT * it) * 16;
            gload_lds16(hsrc + off, (char*)Bh + off);
            gload_lds16(lsrc + off, (char*)Bl + off);
        }
    };

    // gather slot-s edge rows -> Ah/Al (fp32 -> hi/lo bf16 split)
    auto stageA_gather = [&](int s) {
        #pragma unroll
        for (int it = 0; it < 8; ++it) {
            int c = t + NT * it;                // 4096 float4s
            int m = c >> 5, f4 = c & 31;
            int mg = blkTile * 128 + m; mg = (mg < M_) ? mg : (M_ - 1);
            const int* ip = idxp + (((b * M_ + mg) * KS + s) << 1);
            int ii = ip[0], jj = ip[1];
            const float4* row = (const float4*)(e_emb + (((size_t)b * N_ + ii) * N_ + jj) * H_);
            float4 v = row[f4];
            float va[4] = {v.x, v.y, v.z, v.w};
            unsigned short hs[4], ls[4];
            #pragma unroll
            for (int r2 = 0; r2 < 4; ++r2) {
                hs[r2] = f2bf(va[r2]);
                ls[r2] = f2bf(va[r2] - bf2f(hs[r2]));
            }
            uint2 hw, lw;
            hw.x = hs[0] | ((unsigned)hs[1] << 16); hw.y = hs[2] | ((unsigned)hs[3] << 16);
            lw.x = ls[0] | ((unsigned)ls[1] << 16); lw.y = ls[2] | ((unsigned)ls[3] << 16);
            int off = m * 256 + ((f4 * 8) ^ ((m & 15) << 4));
            *(uint2*)((char*)Ah + off) = hw;
            *(uint2*)((char*)Al + off) = lw;
        }
    };

    // one K=128 unit: acc(+)= WT_frag x actT_frag  (computes C^T tiles)
    auto runUnit = [&]() {
        const int nrow  = ntile * 32 + l31;
        const int mrow  = mhalf * 64 + l31;
        const int nbase = nrow * 256, Xn = (nrow & 15) << 4;
        const int mbase = mrow * 256, Xm = (mrow & 15) << 4;
        #pragma unroll
        for (int ks = 0; ks < 8; ++ks) {
            int ka   = ks * 32 + oct * 16;       // k byte offset within row
            int offW = nbase + (ka ^ Xn);
            int offA = mbase + (ka ^ Xm);
            bf16x8 wh  = *(const bf16x8*)((const char*)Bh + offW);
            bf16x8 wl  = *(const bf16x8*)((const char*)Bl + offW);
            bf16x8 a0h = *(const bf16x8*)((const char*)Ah + offA);
            bf16x8 a0l = *(const bf16x8*)((const char*)Al + offA);
            bf16x8 a1h = *(const bf16x8*)((const char*)Ah + offA + 32 * 256);
            bf16x8 a1l = *(const bf16x8*)((const char*)Al + offA + 32 * 256);
            acc0 = __builtin_amdgcn_mfma_f32_32x32x16_bf16(wh, a0h, acc0, 0, 0, 0);
            acc0 = __builtin_amdgcn_mfma_f32_32x32x16_bf16(wh, a0l, acc0, 0, 0, 0);
            acc0 = __builtin_amdgcn_mfma_f32_32x32x16_bf16(wl, a0h, acc0, 0, 0, 0);
            acc1 = __builtin_amdgcn_mfma_f32_32x32x16_bf16(wh, a1h, acc1, 0, 0, 0);
            acc1 = __builtin_amdgcn_mfma_f32_32x32x16_bf16(wh, a1l, acc1, 0, 0, 0);
            acc1 = __builtin_amdgcn_mfma_f32_32x32x16_bf16(wl, a1h, acc1, 0, 0, 0);
        }
    };

    // acc (=C^T: lane col = m, regs = n) -> bias/act -> hi/lo bf16 -> Ah/Al
    auto writeback = [&](int biasSlot, bool doRelu) {
        const float* bp = &bias_all[biasSlot * H_];
        #pragma unroll
        for (int tl = 0; tl < 2; ++tl) {
            int m  = mhalf * 64 + tl * 32 + l31;
            int mb = m * 256, Xm2 = (m & 15) << 4;
            #pragma unroll
            for (int q = 0; q < 4; ++q) {
                int n0 = ntile * 32 + q * 8 + oct * 4;   // 4 consecutive n
                float4 bq = *(const float4*)&bp[n0];
                float ba[4] = {bq.x, bq.y, bq.z, bq.w};
                unsigned short hs[4], ls[4];
                #pragma unroll
                for (int r2 = 0; r2 < 4; ++r2) {
                    float v = (tl ? acc1[q * 4 + r2] : acc0[q * 4 + r2]) + ba[r2];
                    if (doRelu) v = fmaxf(v, 0.f);
                    hs[r2] = f2bf(v);
                    ls[r2] = f2bf(v - bf2f(hs[r2]));
                }
                uint2 hw, lw;
                hw.x = hs[0] | ((unsigned)hs[1] << 16); hw.y = hs[2] | ((unsigned)hs[3] << 16);
                lw.x = ls[0] | ((unsigned)ls[1] << 16); lw.y = ls[2] | ((unsigned)ls[3] << 16);
                int off = mb + ((n0 * 2) ^ Xm2);
                *(uint2*)((char*)Ah + off) = hw;
                *(uint2*)((char*)Al + off) = lw;
            }
        }
    };

    // ---- GEMM1: stream K over edge slots; B issued async, hidden under gather ----
    for (int s = 0; s < KS; ++s) {
        stageB(w1t + s * WIN_U);    // async issue first
        stageA_gather(s);           // heavy phase hides B latency
        __syncthreads();            // drains vmcnt + lds writes
        runUnit();
        __syncthreads();
    }
    // ---- chained 128x128 layers: B issued async, hidden under writeback ----
    stageB(w2t);  writeback(0, true);  __syncthreads(); zeroAcc(); runUnit(); __syncthreads();
    stageB(AW1T); writeback(1, false); __syncthreads(); zeroAcc(); runUnit(); __syncthreads();
    stageB(AW2T); writeback(2, true);  __syncthreads(); zeroAcc(); runUnit(); __syncthreads();
    stageB(AW3T); writeback(3, true);  __syncthreads(); zeroAcc(); runUnit(); __syncthreads();

    // ---- final: logit = relu(acc + an_b3) . Wo + bo, straight from accumulators ----
    float p0 = 0.f, p1 = 0.f;
    {
        const float* b3p = &bias_all[4 * H_];
        const float* wop = &bias_all[5 * H_];
        #pragma unroll
        for (int q = 0; q < 4; ++q) {
            int n0 = ntile * 32 + q * 8 + oct * 4;
            float4 bq = *(const float4*)&b3p[n0];
            float4 wq = *(const float4*)&wop[n0];
            float ba[4] = {bq.x, bq.y, bq.z, bq.w};
            float wa[4] = {wq.x, wq.y, wq.z, wq.w};
            #pragma unroll
            for (int r2 = 0; r2 < 4; ++r2) {
                p0 += fmaxf(acc0[q * 4 + r2] + ba[r2], 0.f) * wa[r2];
                p1 += fmaxf(acc1[q * 4 + r2] + ba[r2], 0.f) * wa[r2];
            }
        }
    }
    p0 += __shfl_xor(p0, 32);
    p1 += __shfl_xor(p1, 32);
    if (l < 32) {
        red[ntile * H_ + mhalf * 64 + l31]      = p0;
        red[ntile * H_ + mhalf * 64 + 32 + l31] = p1;
    }
    __syncthreads();
    if (t < 128) {
        float sres = red[t] + red[H_ + t] + red[2 * H_ + t] + red[3 * H_ + t] + an_bo[0];
        int mg = blkTile * 128 + t;
        if (mg < M_)
            out[((size_t)(b * 3 + type)) * M_ + mg] = sres;
    }
}

extern "C" void kernel_launch(void* const* d_in, const int* in_sizes, int n_in,
                              void* d_out, int out_size, void* d_ws, size_t ws_size,
                              hipStream_t stream) {
    const float* e_emb     = (const float*)d_in[0];
    const int*   reloc_idx = (const int*)  d_in[1];
    const int*   cross_idx = (const int*)  d_in[2];
    const int*   twopt_idx = (const int*)  d_in[3];
    const float* reloc_W1  = (const float*)d_in[4];
    const float* reloc_b1  = (const float*)d_in[5];
    const float* reloc_W2  = (const float*)d_in[6];
    const float* reloc_b2  = (const float*)d_in[7];
    const float* cross_W1  = (const float*)d_in[8];
    const float* cross_b1  = (const float*)d_in[9];
    const float* cross_W2  = (const float*)d_in[10];
    const float* cross_b2  = (const float*)d_in[11];
    const float* an_W1     = (const float*)d_in[12];
    const float* an_b1     = (const float*)d_in[13];
    const float* an_W2     = (const float*)d_in[14];
    const float* an_b2     = (const float*)d_in[15];
    const float* an_W3     = (const float*)d_in[16];
    const float* an_b3     = (const float*)d_in[17];
    const float* an_Wo     = (const float*)d_in[18];
    const float* an_bo     = (const float*)d_in[19];
    float* out = (float*)d_out;
    unsigned short* wt = (unsigned short*)d_ws;   // needs ~983 KB of ws

    hipLaunchKernelGGL(wt_prep, dim3(960), dim3(256), 0, stream,
                       reloc_W1, reloc_W2, cross_W1, cross_W2, an_W1, an_W2, an_W3, wt);
    hipLaunchKernelGGL(vrp_mfma, dim3(3 * B_ * 16), dim3(NT), 0, stream,
                       e_emb, reloc_idx, cross_idx, twopt_idx,
                       reloc_b1, reloc_b2, cross_b1, cross_b2,
                       an_b1, an_b2, an_b3, an_Wo, an_bo, wt, out);
}